// Round 3
// baseline (980.467 us; speedup 1.0000x reference)
//
#include <hip/hip_runtime.h>
#include <math.h>

typedef short bf16x8 __attribute__((ext_vector_type(8)));
typedef float f32x4 __attribute__((ext_vector_type(4)));
typedef unsigned short u16;

#define AS1 __attribute__((address_space(1)))
#define AS3 __attribute__((address_space(3)))

constexpr int kB = 16, kT = 1024, kS = 2048, kH = 1024;
constexpr long NTH = (long)kB * kT * kH;  // 16.8M elems
constexpr long NSH = (long)kB * kS * kH;  // 33.6M elems

// ---------------- bf16 helpers ----------------
__device__ __forceinline__ u16 bf16_rne(float x) {
    unsigned u = __float_as_uint(x);
    u += 0x7FFFu + ((u >> 16) & 1u);
    return (u16)(u >> 16);
}
__device__ __forceinline__ float bf16_f32(u16 h) {
    return __uint_as_float(((unsigned)h) << 16);
}
__device__ __forceinline__ void split2(float x, u16& hi, u16& lo) {
    hi = bf16_rne(x);
    lo = bf16_rne(x - bf16_f32(hi));
}

// =========================================================================
// 256x256xBK=64 8-wave GEMM core, 4-phase-per-K-tile schedule (T2+T3+T4+T5).
// LDS: A,B double-buffered, 128 KiB. Swizzle: (row, colbyte c) at byte
// row*128 + (c ^ ((row&7)<<4)); staged via linear-dest global_load_lds with
// inverse-swizzled per-lane global source (both-sides rule).
// Phase p of tile j: {ds_read subtile; stage 1 half-tile; barrier; lgkm0;
// setprio(1); 16 MFMA; setprio(0); barrier}. vmcnt(4) once per tile (never 0).
// Stage schedule: P1:A-h0(j+1) P2:A-h1(j+1) P3:B-h0(j+2) P4:B-h1(j+2).
// Deaths (barrier-separated): A halves after P3, B halves after P2 -> no race.
// =========================================================================

#define PHASE_PRE()                                          \
    __builtin_amdgcn_sched_barrier(0);                       \
    __builtin_amdgcn_s_barrier();                            \
    asm volatile("s_waitcnt lgkmcnt(0)" ::: "memory");       \
    __builtin_amdgcn_sched_barrier(0);                       \
    __builtin_amdgcn_s_setprio(1);

#define PHASE_POST()                                         \
    __builtin_amdgcn_s_setprio(0);                           \
    __builtin_amdgcn_sched_barrier(0);                       \
    __builtin_amdgcn_s_barrier();

// NT = K'/64 tiles; TPS = tiles per K-segment. Sources pre-offset to (bm,bn).
template <int NT, int TPS>
__device__ __forceinline__ void gemm_core(const u16* a0, const u16* a1, const u16* a2,
                                          long lda,
                                          const u16* b0, const u16* b1, const u16* b2,
                                          long ldb, f32x4 acc[8][4]) {
    __shared__ u16 As[2][256 * 64], Bs[2][256 * 64];
    const int t = threadIdx.x, lane = t & 63, wave = t >> 6;
    const int wr = wave >> 2, wc = wave & 3, l15 = lane & 15, quad = lane >> 4;
    const int swzb = (l15 & 7) << 4;
    const int cbu0 = ((quad * 16) ^ swzb) >> 1;        // u16 offset, k-half 0
    const int cbu1 = ((quad * 16 + 64) ^ swzb) >> 1;   // u16 offset, k-half 1

    auto srcA = [&](int kt) {
        int seg = kt / TPS;
        const u16* p = (seg == 0) ? a0 : (seg == 1 ? a1 : a2);
        return p + (long)(kt % TPS) * 64;
    };
    auto srcB = [&](int kt) {
        int seg = kt / TPS;
        const u16* p = (seg == 0) ? b0 : (seg == 1 ? b1 : b2);
        return p + (long)(kt % TPS) * 64;
    };
    // stage one half-tile (128 rows x 64 cols, 16 KiB) = 2 gll/lane
    auto stageA = [&](int kt, int h, int buf) {
        const u16* g = srcA(kt < NT ? kt : NT - 1) + (long)h * 128 * lda;
        u16* region = &As[buf][h * 8192];
#pragma unroll
        for (int c = 0; c < 2; ++c) {
            int u = c * 512 + t;
            int r = u >> 3, j8 = u & 7;
            const u16* src = g + (long)r * lda + ((j8 ^ (r & 7)) << 3);
            u16* dst = region + c * 4096 + wave * 512;
            __builtin_amdgcn_global_load_lds((AS1 void*)src, (AS3 void*)dst, 16, 0, 0);
        }
    };
    auto stageB = [&](int kt, int h, int buf) {
        const u16* g = srcB(kt < NT ? kt : NT - 1) + (long)h * 128 * ldb;
        u16* region = &Bs[buf][h * 8192];
#pragma unroll
        for (int c = 0; c < 2; ++c) {
            int u = c * 512 + t;
            int r = u >> 3, j8 = u & 7;
            const u16* src = g + (long)r * ldb + ((j8 ^ (r & 7)) << 3);
            u16* dst = region + c * 4096 + wave * 512;
            __builtin_amdgcn_global_load_lds((AS1 void*)src, (AS3 void*)dst, 16, 0, 0);
        }
    };

    // prologue: prime the stage stream (order matters for vmcnt FIFO):
    // B0(0) B1(0) A0(0) A1(0) B0(1) B1(1)  -> vmcnt(4) completes tile 0's set.
    stageB(0, 0, 0); __builtin_amdgcn_sched_barrier(0);
    stageB(0, 1, 0); __builtin_amdgcn_sched_barrier(0);
    stageA(0, 0, 0); __builtin_amdgcn_sched_barrier(0);
    stageA(0, 1, 0); __builtin_amdgcn_sched_barrier(0);
    stageB(1, 0, 1); __builtin_amdgcn_sched_barrier(0);
    stageB(1, 1, 1); __builtin_amdgcn_sched_barrier(0);
    asm volatile("s_waitcnt vmcnt(4)" ::: "memory");
    __builtin_amdgcn_s_barrier();

#pragma unroll 1
    for (int j = 0; j < NT; ++j) {
        const int c = j & 1;
        bf16x8 a[4][2], bA[2][2], bB[2][2];

        auto mfma16 = [&](bf16x8 (&a4)[4][2], bf16x8 (&b2)[2][2], int ih, int jh) {
#pragma unroll
            for (int i2 = 0; i2 < 4; ++i2)
#pragma unroll
                for (int j2 = 0; j2 < 2; ++j2) {
                    acc[ih * 4 + i2][jh * 2 + j2] = __builtin_amdgcn_mfma_f32_16x16x32_bf16(
                        a4[i2][0], b2[j2][0], acc[ih * 4 + i2][jh * 2 + j2], 0, 0, 0);
                    acc[ih * 4 + i2][jh * 2 + j2] = __builtin_amdgcn_mfma_f32_16x16x32_bf16(
                        a4[i2][1], b2[j2][1], acc[ih * 4 + i2][jh * 2 + j2], 0, 0, 0);
                }
        };

        // ---- P1: read a[0..3] + b[0,1]; stage A-h0(j+1); MFMA (ih0,jh0)
#pragma unroll
        for (int i = 0; i < 4; ++i) {
            const u16* base = &As[c][(wr * 128 + i * 16 + l15) * 64];
            a[i][0] = *(const bf16x8*)(base + cbu0);
            a[i][1] = *(const bf16x8*)(base + cbu1);
        }
#pragma unroll
        for (int jj = 0; jj < 2; ++jj) {
            const u16* base = &Bs[c][(wc * 64 + jj * 16 + l15) * 64];
            bA[jj][0] = *(const bf16x8*)(base + cbu0);
            bA[jj][1] = *(const bf16x8*)(base + cbu1);
        }
        stageA(j + 1, 0, c ^ 1);
        PHASE_PRE()
        mfma16(a, bA, 0, 0);
        PHASE_POST()

        // ---- P2: read b[2,3]; stage A-h1(j+1); MFMA (ih0,jh1)
#pragma unroll
        for (int jj = 0; jj < 2; ++jj) {
            const u16* base = &Bs[c][(wc * 64 + (2 + jj) * 16 + l15) * 64];
            bB[jj][0] = *(const bf16x8*)(base + cbu0);
            bB[jj][1] = *(const bf16x8*)(base + cbu1);
        }
        stageA(j + 1, 1, c ^ 1);
        PHASE_PRE()
        mfma16(a, bB, 0, 1);
        PHASE_POST()

        // ---- P3: read a[4..7]; stage B-h0(j+2); MFMA (ih1,jh0)
#pragma unroll
        for (int i = 0; i < 4; ++i) {
            const u16* base = &As[c][(wr * 128 + (4 + i) * 16 + l15) * 64];
            a[i][0] = *(const bf16x8*)(base + cbu0);
            a[i][1] = *(const bf16x8*)(base + cbu1);
        }
        stageB(j + 2, 0, c);
        PHASE_PRE()
        mfma16(a, bA, 1, 0);
        PHASE_POST()

        // ---- P4: no reads; stage B-h1(j+2); MFMA (ih1,jh1); tile-boundary vmcnt
        stageB(j + 2, 1, c);
        __builtin_amdgcn_sched_barrier(0);
        __builtin_amdgcn_s_barrier();
        __builtin_amdgcn_s_setprio(1);
        mfma16(a, bB, 1, 1);
        __builtin_amdgcn_s_setprio(0);
        __builtin_amdgcn_sched_barrier(0);
        asm volatile("s_waitcnt vmcnt(4)" ::: "memory");
        __builtin_amdgcn_s_barrier();
    }
    asm volatile("s_waitcnt vmcnt(0)" ::: "memory");
}

// ---------------- GEMM kernels ----------------
// q = output @ attn_w^T in split precision: K' = 3H, segs (oh,awh),(ol,awh),(oh,awl)
__global__ __launch_bounds__(512, 2) void k_gemm_q(const u16* __restrict__ oh,
                                                   const u16* __restrict__ ol,
                                                   const u16* __restrict__ awh,
                                                   const u16* __restrict__ awl,
                                                   u16* __restrict__ Qhi,
                                                   u16* __restrict__ Qlo) {
    const long bm = (long)blockIdx.y * 256, bn = (long)blockIdx.x * 256;
    f32x4 acc[8][4] = {};
    gemm_core<48, 16>(oh + bm * kH, ol + bm * kH, oh + bm * kH, kH,
                      awh + bn * kH, awh + bn * kH, awl + bn * kH, kH, acc);
    const int t = threadIdx.x, lane = t & 63, wave = t >> 6;
    const int wr = wave >> 2, wc = wave & 3, l15 = lane & 15, quad = lane >> 4;
#pragma unroll
    for (int i = 0; i < 8; ++i)
#pragma unroll
        for (int j = 0; j < 4; ++j)
#pragma unroll
            for (int r = 0; r < 4; ++r) {
                long m = bm + wr * 128 + i * 16 + quad * 4 + r;
                long n = bn + wc * 64 + j * 16 + l15;
                float v = acc[i][j][r];
                u16 h = bf16_rne(v);
                Qhi[m * kH + n] = h;
                Qlo[m * kH + n] = bf16_rne(v - bf16_f32(h));
            }
}

// logits = q @ ctx^T per batch, split: K' = 3H, segs (qh,ch),(ql,ch),(qh,cl)
// 1D grid 512, XCD-aware decode: each XCD owns 2 whole batches.
__global__ __launch_bounds__(512, 2) void k_gemm_logits(const u16* __restrict__ Qh,
                                                        const u16* __restrict__ Ql,
                                                        const u16* __restrict__ Ch,
                                                        const u16* __restrict__ Cl,
                                                        float* __restrict__ Cout) {
    const int l = blockIdx.x;
    const int xcd = l & 7, slot = l >> 3;
    const int z = xcd + ((slot >> 5) << 3);
    const int inner = slot & 31;
    const long bn = (long)(inner & 7) * 256;   // S tiles (8)
    const long bm = (long)(inner >> 3) * 256;  // T tiles (4)
    const u16* qh = Qh + (long)z * kT * kH + bm * kH;
    const u16* ql = Ql + (long)z * kT * kH + bm * kH;
    const u16* ch = Ch + (long)z * kS * kH + bn * kH;
    const u16* cl = Cl + (long)z * kS * kH + bn * kH;
    f32x4 acc[8][4] = {};
    gemm_core<48, 16>(qh, ql, qh, kH, ch, ch, cl, kH, acc);
    float* C = Cout + (long)z * kT * kS;
    const int t = threadIdx.x, lane = t & 63, wave = t >> 6;
    const int wr = wave >> 2, wc = wave & 3, l15 = lane & 15, quad = lane >> 4;
#pragma unroll
    for (int i = 0; i < 8; ++i)
#pragma unroll
        for (int j = 0; j < 4; ++j)
#pragma unroll
            for (int r = 0; r < 4; ++r) {
                long m = bm + wr * 128 + i * 16 + quad * 4 + r;
                long n = bn + wc * 64 + j * 16 + l15;
                C[m * kS + n] = acc[i][j][r];
            }
}

// mix = attn @ ctx per batch (plain bf16): K' = S, single segment
__global__ __launch_bounds__(512, 2) void k_gemm_mix(const u16* __restrict__ attnb,
                                                     const u16* __restrict__ ctxT,
                                                     u16* __restrict__ Mixb) {
    const int l = blockIdx.x;
    const int xcd = l & 7, slot = l >> 3;
    const int z = xcd + ((slot >> 4) << 3);
    const int inner = slot & 15;
    const long bn = (long)(inner & 3) * 256;   // H tiles (4)
    const long bm = (long)(inner >> 2) * 256;  // T tiles (4)
    const u16* Ab = attnb + (long)z * kT * kS + bm * kS;
    const u16* Bb = ctxT + (long)z * kH * kS + bn * kS;
    f32x4 acc[8][4] = {};
    gemm_core<32, 32>(Ab, Ab, Ab, kS, Bb, Bb, Bb, kS, acc);
    u16* C = Mixb + (long)z * kT * kH;
    const int t = threadIdx.x, lane = t & 63, wave = t >> 6;
    const int wr = wave >> 2, wc = wave & 3, l15 = lane & 15, quad = lane >> 4;
#pragma unroll
    for (int i = 0; i < 8; ++i)
#pragma unroll
        for (int j = 0; j < 4; ++j)
#pragma unroll
            for (int r = 0; r < 4; ++r) {
                long m = bm + wr * 128 + i * 16 + quad * 4 + r;
                long n = bn + wc * 64 + j * 16 + l15;
                C[m * kH + n] = bf16_rne(acc[i][j][r]);
            }
}

// out = tanh([mix|q] @ lw^T + lb): K' = 2H, segs (mix,lw[:, :H]),(q,lw[:, H:])
__global__ __launch_bounds__(512, 2) void k_gemm_out(const u16* __restrict__ mixc,
                                                     const u16* __restrict__ qc,
                                                     const u16* __restrict__ lwb,
                                                     const float* __restrict__ bias,
                                                     float* __restrict__ Out) {
    const long bm = (long)blockIdx.y * 256, bn = (long)blockIdx.x * 256;
    f32x4 acc[8][4] = {};
    gemm_core<32, 16>(mixc + bm * kH, qc + bm * kH, qc + bm * kH, kH,
                      lwb + bn * 2 * kH, lwb + bn * 2 * kH + kH, lwb + bn * 2 * kH + kH,
                      2 * kH, acc);
    const int t = threadIdx.x, lane = t & 63, wave = t >> 6;
    const int wr = wave >> 2, wc = wave & 3, l15 = lane & 15, quad = lane >> 4;
#pragma unroll
    for (int j = 0; j < 4; ++j) {
        long n = bn + wc * 64 + j * 16 + l15;
        float bj = bias[n];
#pragma unroll
        for (int i = 0; i < 8; ++i)
#pragma unroll
            for (int r = 0; r < 4; ++r) {
                long m = bm + wr * 128 + i * 16 + quad * 4 + r;
                Out[m * kH + n] = tanhf(acc[i][j][r] + bj);
            }
    }
}

// ---------------- prepasses ----------------
__global__ __launch_bounds__(256) void split_f32(const float* __restrict__ src,
                                                 u16* __restrict__ hi, u16* __restrict__ lo,
                                                 long n4) {
    for (long i = (long)blockIdx.x * 256 + threadIdx.x; i < n4; i += (long)gridDim.x * 256) {
        float4 v = ((const float4*)src)[i];
        u16 h0, l0, h1, l1, h2, l2, h3, l3;
        split2(v.x, h0, l0); split2(v.y, h1, l1);
        split2(v.z, h2, l2); split2(v.w, h3, l3);
        ((ushort4*)hi)[i] = make_ushort4(h0, h1, h2, h3);
        ((ushort4*)lo)[i] = make_ushort4(l0, l1, l2, l3);
    }
}

__global__ __launch_bounds__(256) void cvt_f32(const float* __restrict__ src,
                                               u16* __restrict__ dst, long n4) {
    for (long i = (long)blockIdx.x * 256 + threadIdx.x; i < n4; i += (long)gridDim.x * 256) {
        float4 v = ((const float4*)src)[i];
        ((ushort4*)dst)[i] = make_ushort4(bf16_rne(v.x), bf16_rne(v.y),
                                          bf16_rne(v.z), bf16_rne(v.w));
    }
}

__global__ __launch_bounds__(256) void copy16(const uint4* __restrict__ src,
                                              uint4* __restrict__ dst, long n) {
    for (long i = (long)blockIdx.x * 256 + threadIdx.x; i < n; i += (long)gridDim.x * 256)
        dst[i] = src[i];
}

// bf16 [B,S,H] -> [B,H,S] (ctxT == transpose of ctx_hi bit-exactly)
__global__ __launch_bounds__(256) void transpose_bf16(const u16* __restrict__ in,
                                                      u16* __restrict__ outp) {
    __shared__ u16 tile[64 * 72];
    const int t = threadIdx.x;
    const u16* src = in + (long)blockIdx.z * kS * kH + (long)(blockIdx.y * 64) * kH
                     + blockIdx.x * 64;
#pragma unroll
    for (int it = 0; it < 2; ++it) {
        int idx = it * 256 + t;            // 512 chunks of 8 u16 = 64 s-rows x 8
        int s = idx >> 3, hc = (idx & 7) << 3;
        uint4 v = *(const uint4*)(src + (long)s * kH + hc);
        const u16* pv = (const u16*)&v;
#pragma unroll
        for (int k = 0; k < 8; ++k) tile[(hc + k) * 72 + s] = pv[k];
    }
    __syncthreads();
    u16* dst = outp + (long)blockIdx.z * kH * kS + (long)(blockIdx.x * 64) * kS
               + blockIdx.y * 64;
#pragma unroll
    for (int it = 0; it < 2; ++it) {
        int idx = it * 256 + t;
        int h = idx >> 3, sc = (idx & 7) << 3;
        *(uint4*)(dst + (long)h * kS + sc) = *(const uint4*)&tile[h * 72 + sc];
    }
}

// ---------------- softmax over S, in place; emits bf16 copy ----------------
__global__ __launch_bounds__(256) void softmax_rows(float* __restrict__ P,
                                                    u16* __restrict__ Pb) {
    __shared__ float red[4];
    float* p = P + (long)blockIdx.x * kS;
    u16* pb = Pb + (long)blockIdx.x * kS;
    const int t = threadIdx.x;

    float4 v0 = ((const float4*)p)[t];
    float4 v1 = ((const float4*)p)[t + 256];

    float m = fmaxf(fmaxf(fmaxf(v0.x, v0.y), fmaxf(v0.z, v0.w)),
                    fmaxf(fmaxf(v1.x, v1.y), fmaxf(v1.z, v1.w)));
#pragma unroll
    for (int o = 32; o > 0; o >>= 1) m = fmaxf(m, __shfl_xor(m, o));
    if ((t & 63) == 0) red[t >> 6] = m;
    __syncthreads();
    m = fmaxf(fmaxf(red[0], red[1]), fmaxf(red[2], red[3]));
    __syncthreads();

    v0.x = expf(v0.x - m); v0.y = expf(v0.y - m);
    v0.z = expf(v0.z - m); v0.w = expf(v0.w - m);
    v1.x = expf(v1.x - m); v1.y = expf(v1.y - m);
    v1.z = expf(v1.z - m); v1.w = expf(v1.w - m);

    float s = v0.x + v0.y + v0.z + v0.w + v1.x + v1.y + v1.z + v1.w;
#pragma unroll
    for (int o = 32; o > 0; o >>= 1) s += __shfl_xor(s, o);
    if ((t & 63) == 0) red[t >> 6] = s;
    __syncthreads();
    s = red[0] + red[1] + red[2] + red[3];

    const float inv = 1.0f / s;
    v0.x *= inv; v0.y *= inv; v0.z *= inv; v0.w *= inv;
    v1.x *= inv; v1.y *= inv; v1.z *= inv; v1.w *= inv;

    ((float4*)p)[t]       = v0;
    ((float4*)p)[t + 256] = v1;
    ((ushort4*)pb)[t]       = make_ushort4(bf16_rne(v0.x), bf16_rne(v0.y),
                                           bf16_rne(v0.z), bf16_rne(v0.w));
    ((ushort4*)pb)[t + 256] = make_ushort4(bf16_rne(v1.x), bf16_rne(v1.y),
                                           bf16_rne(v1.z), bf16_rne(v1.w));
}

// ---------------------------------------------------------------------------
// Lifetime plan (ws = 128 MiB; d_out = out 67MB | attn 134MB):
//  1. ws = [ctx_hi | ctx_lo]; attn-region scratch = [oh|ol|awh|awl]
//  2. k_gemm_q -> [q_hi|q_lo] in out-region
//  3. k_gemm_logits -> attn fp32 (overwrites oh/ol/aw scratch)
//  4. transpose_bf16: ctx_hi -> ctxT at ws[NSH:] (ctx_lo dead)
//  5. softmax: attn in place + attnb -> ws[0:NSH] (ctx_hi dead)
//  6. k_gemm_mix(attnb, ctxT) -> mixb = q_lo slot
//  7. copy [q_hi|mixb] -> ws[0:2*NTH] = [q_c|mix_c]; lwb -> ws+2*NTH (ctxT dead)
//  8. k_gemm_out(mix_c, q_c, lwb) -> out (q scratch dead)
extern "C" void kernel_launch(void* const* d_in, const int* in_sizes, int n_in,
                              void* d_out, int out_size, void* d_ws, size_t ws_size,
                              hipStream_t stream) {
    (void)in_sizes; (void)n_in; (void)out_size; (void)ws_size;

    const float* outp = (const float*)d_in[0];  // [B,T,H]
    const float* ctx  = (const float*)d_in[1];  // [B,S,H]
    const float* aw   = (const float*)d_in[2];  // [H,H]
    const float* lw   = (const float*)d_in[3];  // [H,2H]
    const float* lb   = (const float*)d_in[4];  // [H]

    float* out  = (float*)d_out;
    float* attn = out + NTH;

    u16* ws = (u16*)d_ws;
    u16* ctx_hi = ws;
    u16* ctx_lo = ws + NSH;
    u16* q_hi = (u16*)out;
    u16* q_lo = q_hi + NTH;
    u16* oh  = (u16*)attn;
    u16* ol  = oh + NTH;
    u16* awh = ol + NTH;
    u16* awl = awh + (long)kH * kH;
    u16* ctxT  = ws + NSH;
    u16* attnb = ws;
    u16* mixb  = q_lo;
    u16* q_c   = ws;
    u16* mix_c = ws + NTH;
    u16* lwb   = ws + 2 * NTH;

    split_f32<<<2048, 256, 0, stream>>>(ctx, ctx_hi, ctx_lo, NSH / 4);
    split_f32<<<2048, 256, 0, stream>>>(outp, oh, ol, NTH / 4);
    split_f32<<<1024, 256, 0, stream>>>(aw, awh, awl, (long)kH * kH / 4);

    k_gemm_q<<<dim3(kH / 256, (kB * kT) / 256), 512, 0, stream>>>(oh, ol, awh, awl,
                                                                  q_hi, q_lo);
    k_gemm_logits<<<512, 512, 0, stream>>>(q_hi, q_lo, ctx_hi, ctx_lo, attn);

    transpose_bf16<<<dim3(kH / 64, kS / 64, kB), 256, 0, stream>>>(ctx_hi, ctxT);
    softmax_rows<<<kB * kT, 256, 0, stream>>>(attn, attnb);

    k_gemm_mix<<<256, 512, 0, stream>>>(attnb, ctxT, mixb);

    copy16<<<2048, 256, 0, stream>>>((const uint4*)q_hi, (uint4*)ws, (2 * NTH) / 8);
    cvt_f32<<<2048, 256, 0, stream>>>(lw, lwb, (long)kH * 2 * kH / 4);

    k_gemm_out<<<dim3(kH / 256, (kB * kT) / 256), 512, 0, stream>>>(mix_c, q_c, lwb, lb, out);
}

// Round 4
// 925.069 us; speedup vs baseline: 1.0599x; 1.0599x over previous
//
#include <hip/hip_runtime.h>
#include <math.h>

typedef short bf16x8 __attribute__((ext_vector_type(8)));
typedef float f32x4 __attribute__((ext_vector_type(4)));
typedef unsigned short u16;

#define AS1 __attribute__((address_space(1)))
#define AS3 __attribute__((address_space(3)))

constexpr int kB = 16, kT = 1024, kS = 2048, kH = 1024;
constexpr long NTH = (long)kB * kT * kH;  // 16.8M elems
constexpr long NSH = (long)kB * kS * kH;  // 33.6M elems

// ---------------- bf16 helpers ----------------
__device__ __forceinline__ u16 bf16_rne(float x) {
    unsigned u = __float_as_uint(x);
    u += 0x7FFFu + ((u >> 16) & 1u);
    return (u16)(u >> 16);
}
__device__ __forceinline__ float bf16_f32(u16 h) {
    return __uint_as_float(((unsigned)h) << 16);
}
__device__ __forceinline__ void split2(float x, u16& hi, u16& lo) {
    hi = bf16_rne(x);
    lo = bf16_rne(x - bf16_f32(hi));
}

// =========================================================================
// CORE A (round-2, measured): 256x256xBK=64, 2 barriers/tile, counted vmcnt.
// =========================================================================
__device__ __forceinline__ void stage_mat(const u16* __restrict__ g, long ld,
                                          u16* lds, int t, int wave) {
#pragma unroll
    for (int c = 0; c < 4; ++c) {
        int u = c * 512 + t;          // 16B unit, 8 per 128B row
        int r = u >> 3, j = u & 7;
        const u16* src = g + (long)r * ld + ((j ^ (r & 7)) << 3);  // inverse swizzle
        u16* dst = lds + c * 4096 + wave * 512;                    // linear dest
        __builtin_amdgcn_global_load_lds((AS1 void*)src, (AS3 void*)dst, 16, 0, 0);
    }
}

__device__ __forceinline__ void tile_compute(const u16* As, const u16* Bs,
                                             f32x4 acc[8][4], int wr, int wc,
                                             int l15, int cbu0, int cbu1) {
    bf16x8 b[4][2];
#pragma unroll
    for (int j = 0; j < 4; ++j) {
        const u16* base = Bs + (wc * 64 + j * 16 + l15) * 64;
        b[j][0] = *(const bf16x8*)(base + cbu0);
        b[j][1] = *(const bf16x8*)(base + cbu1);
    }
#pragma unroll
    for (int qm = 0; qm < 2; ++qm) {
        bf16x8 a[4][2];
#pragma unroll
        for (int i = 0; i < 4; ++i) {
            const u16* base = As + (wr * 128 + qm * 64 + i * 16 + l15) * 64;
            a[i][0] = *(const bf16x8*)(base + cbu0);
            a[i][1] = *(const bf16x8*)(base + cbu1);
        }
        __builtin_amdgcn_s_setprio(1);
#pragma unroll
        for (int i = 0; i < 4; ++i)
#pragma unroll
            for (int j = 0; j < 4; ++j) {
                acc[qm * 4 + i][j] = __builtin_amdgcn_mfma_f32_16x16x32_bf16(
                    a[i][0], b[j][0], acc[qm * 4 + i][j], 0, 0, 0);
                acc[qm * 4 + i][j] = __builtin_amdgcn_mfma_f32_16x16x32_bf16(
                    a[i][1], b[j][1], acc[qm * 4 + i][j], 0, 0, 0);
            }
        __builtin_amdgcn_s_setprio(0);
    }
}

#define WAIT_VM(N)                                            \
    asm volatile("s_waitcnt vmcnt(" #N ")" ::: "memory");     \
    __builtin_amdgcn_s_barrier();                             \
    __builtin_amdgcn_sched_barrier(0);

#define POST_BARRIER()                                        \
    __builtin_amdgcn_sched_barrier(0);                        \
    __builtin_amdgcn_s_barrier();                             \
    __builtin_amdgcn_sched_barrier(0);

template <int NT, int TPS>
__device__ __forceinline__ void gemm_core(const u16* a0, const u16* a1, const u16* a2,
                                          long lda,
                                          const u16* b0, const u16* b1, const u16* b2,
                                          long ldb, f32x4 acc[8][4]) {
    __shared__ u16 As[2][256 * 64], Bs[2][256 * 64];
    const int t = threadIdx.x, lane = t & 63, wave = t >> 6;
    const int wr = wave >> 2, wc = wave & 3, l15 = lane & 15, quad = lane >> 4;
    const int swzb = (l15 & 7) << 4;
    const int cbu0 = ((quad * 16) ^ swzb) >> 1;        // u16 offset, k-half 0
    const int cbu1 = ((quad * 16 + 64) ^ swzb) >> 1;   // u16 offset, k-half 1

    auto srcA = [&](int kt) {
        int seg = kt / TPS;
        const u16* p = (seg == 0) ? a0 : (seg == 1 ? a1 : a2);
        return p + (long)(kt % TPS) * 64;
    };
    auto srcB = [&](int kt) {
        int seg = kt / TPS;
        const u16* p = (seg == 0) ? b0 : (seg == 1 ? b1 : b2);
        return p + (long)(kt % TPS) * 64;
    };

    stage_mat(srcA(0), lda, As[0], t, wave);
    stage_mat(srcB(0), ldb, Bs[0], t, wave);
    __builtin_amdgcn_sched_barrier(0);
    stage_mat(srcA(1), lda, As[1], t, wave);
    stage_mat(srcB(1), ldb, Bs[1], t, wave);
    __builtin_amdgcn_sched_barrier(0);

#pragma unroll 1
    for (int it = 0; it < NT / 2 - 1; ++it) {
        int kt = 2 * it;
        WAIT_VM(8)
        tile_compute(As[0], Bs[0], acc, wr, wc, l15, cbu0, cbu1);
        POST_BARRIER()
        stage_mat(srcA(kt + 2), lda, As[0], t, wave);
        stage_mat(srcB(kt + 2), ldb, Bs[0], t, wave);

        WAIT_VM(8)
        tile_compute(As[1], Bs[1], acc, wr, wc, l15, cbu0, cbu1);
        POST_BARRIER()
        stage_mat(srcA(kt + 3), lda, As[1], t, wave);
        stage_mat(srcB(kt + 3), ldb, Bs[1], t, wave);
    }
    WAIT_VM(8)
    tile_compute(As[0], Bs[0], acc, wr, wc, l15, cbu0, cbu1);
    WAIT_VM(0)
    tile_compute(As[1], Bs[1], acc, wr, wc, l15, cbu0, cbu1);
}

// =========================================================================
// CORE B (new, logits only): 256x256, K-split phases (K=32 each), uniform
// vmcnt(4) per phase, stage-into-dead-buffer, 2 barriers/tile.
// LDS layout: [buf][khalf][256 rows][32 cols], 64B rows, swizzle
// c16' = c16 ^ ((row>>1)&3)  (16B units within the 64B row).
// Per-thread FIFO invariant at each phase's vmcnt(4): outstanding =
// {this phase's 4 loads (drained), next phase's 4 (kept)}.
// =========================================================================
template <int NT, int TPS>
__device__ __forceinline__ void gemm_core_ks(const u16* a0, const u16* a1, const u16* a2,
                                             long lda,
                                             const u16* b0, const u16* b1, const u16* b2,
                                             long ldb, f32x4 acc[8][4]) {
    __shared__ u16 As[2][2][256 * 32], Bs[2][2][256 * 32];
    const int t = threadIdx.x, lane = t & 63, wave = t >> 6;
    const int wr = wave >> 2, wc = wave & 3, l15 = lane & 15, quad = lane >> 4;
    // swizzled u16 col offset (same for all fragment rows: row>>1&3 == l15>>1&3)
    const int cu = (quad ^ ((l15 >> 1) & 3)) << 3;

    auto srcA = [&](int kt) {
        int seg = kt / TPS;
        const u16* p = (seg == 0) ? a0 : (seg == 1 ? a1 : a2);
        return p + (long)(kt % TPS) * 64;
    };
    auto srcB = [&](int kt) {
        int seg = kt / TPS;
        const u16* p = (seg == 0) ? b0 : (seg == 1 ? b1 : b2);
        return p + (long)(kt % TPS) * 64;
    };
    // stage one k-half of one matrix tile: 256 rows x 32 cols = 16KB = 2 gll/thread
    auto stageH = [&](const u16* g, long ld, int kh, u16* region) {
        const u16* gh = g + kh * 32;
#pragma unroll
        for (int c = 0; c < 2; ++c) {
            int u = c * 512 + t;
            int r = u >> 2, c16 = u & 3;
            const u16* src = gh + (long)r * ld + ((c16 ^ ((r >> 1) & 3)) << 3);
            u16* dst = region + c * 4096 + wave * 512;   // linear dest, lane*16B auto
            __builtin_amdgcn_global_load_lds((AS1 void*)src, (AS3 void*)dst, 16, 0, 0);
        }
    };

    // prologue: both k-halves of tile 0 (8 loads/thread in FIFO order k0, k1)
    stageH(srcA(0), lda, 0, As[0][0]);
    stageH(srcB(0), ldb, 0, Bs[0][0]);
    __builtin_amdgcn_sched_barrier(0);
    stageH(srcA(0), lda, 1, As[0][1]);
    stageH(srcB(0), ldb, 1, Bs[0][1]);
    __builtin_amdgcn_sched_barrier(0);

#pragma unroll 1
    for (int j = 0; j < NT; ++j) {
        const int buf = j & 1;
        const int skt = (j + 1 < NT) ? j + 1 : NT - 1;  // clamped: garbage into dead buf
#pragma unroll
        for (int kh = 0; kh < 2; ++kh) {
            asm volatile("s_waitcnt vmcnt(4)" ::: "memory");
            __builtin_amdgcn_s_barrier();
            __builtin_amdgcn_sched_barrier(0);
            // stage next tile's matching k-half into the dead (opposite) buffer
            stageH(srcA(skt), lda, kh, As[buf ^ 1][kh]);
            stageH(srcB(skt), ldb, kh, Bs[buf ^ 1][kh]);
            // fragments for this k-half
            bf16x8 a[8], b[4];
#pragma unroll
            for (int i = 0; i < 8; ++i)
                a[i] = *(const bf16x8*)(&As[buf][kh][(wr * 128 + i * 16 + l15) * 32 + cu]);
#pragma unroll
            for (int jj = 0; jj < 4; ++jj)
                b[jj] = *(const bf16x8*)(&Bs[buf][kh][(wc * 64 + jj * 16 + l15) * 32 + cu]);
            __builtin_amdgcn_s_setprio(1);
#pragma unroll
            for (int i = 0; i < 8; ++i)
#pragma unroll
                for (int jj = 0; jj < 4; ++jj)
                    acc[i][jj] = __builtin_amdgcn_mfma_f32_16x16x32_bf16(
                        a[i], b[jj], acc[i][jj], 0, 0, 0);
            __builtin_amdgcn_s_setprio(0);
        }
    }
    asm volatile("s_waitcnt vmcnt(0)" ::: "memory");
}

// ---------------- GEMM kernels ----------------
// q = output @ attn_w^T in split precision: K' = 3H, segs (oh,awh),(ol,awh),(oh,awl)
__global__ __launch_bounds__(512, 2) void k_gemm_q(const u16* __restrict__ oh,
                                                   const u16* __restrict__ ol,
                                                   const u16* __restrict__ awh,
                                                   const u16* __restrict__ awl,
                                                   u16* __restrict__ Qhi,
                                                   u16* __restrict__ Qlo) {
    const long bm = (long)blockIdx.y * 256, bn = (long)blockIdx.x * 256;
    f32x4 acc[8][4] = {};
    gemm_core<48, 16>(oh + bm * kH, ol + bm * kH, oh + bm * kH, kH,
                      awh + bn * kH, awh + bn * kH, awl + bn * kH, kH, acc);
    const int t = threadIdx.x, lane = t & 63, wave = t >> 6;
    const int wr = wave >> 2, wc = wave & 3, l15 = lane & 15, quad = lane >> 4;
#pragma unroll
    for (int i = 0; i < 8; ++i)
#pragma unroll
        for (int j = 0; j < 4; ++j)
#pragma unroll
            for (int r = 0; r < 4; ++r) {
                long m = bm + wr * 128 + i * 16 + quad * 4 + r;
                long n = bn + wc * 64 + j * 16 + l15;
                float v = acc[i][j][r];
                u16 h = bf16_rne(v);
                Qhi[m * kH + n] = h;
                Qlo[m * kH + n] = bf16_rne(v - bf16_f32(h));
            }
}

// logits = q @ ctx^T per batch, split: K' = 3H, segs (qh,ch),(ql,ch),(qh,cl)
// NEW k-split core. 1D grid 512, XCD-aware decode.
__global__ __launch_bounds__(512, 2) void k_gemm_logits(const u16* __restrict__ Qh,
                                                        const u16* __restrict__ Ql,
                                                        const u16* __restrict__ Ch,
                                                        const u16* __restrict__ Cl,
                                                        float* __restrict__ Cout) {
    const int l = blockIdx.x;
    const int xcd = l & 7, slot = l >> 3;
    const int z = xcd + ((slot >> 5) << 3);
    const int inner = slot & 31;
    const long bn = (long)(inner & 7) * 256;   // S tiles (8)
    const long bm = (long)(inner >> 3) * 256;  // T tiles (4)
    const u16* qh = Qh + (long)z * kT * kH + bm * kH;
    const u16* ql = Ql + (long)z * kT * kH + bm * kH;
    const u16* ch = Ch + (long)z * kS * kH + bn * kH;
    const u16* cl = Cl + (long)z * kS * kH + bn * kH;
    f32x4 acc[8][4] = {};
    gemm_core_ks<48, 16>(qh, ql, qh, kH, ch, ch, cl, kH, acc);
    float* C = Cout + (long)z * kT * kS;
    const int t = threadIdx.x, lane = t & 63, wave = t >> 6;
    const int wr = wave >> 2, wc = wave & 3, l15 = lane & 15, quad = lane >> 4;
#pragma unroll
    for (int i = 0; i < 8; ++i)
#pragma unroll
        for (int j = 0; j < 4; ++j)
#pragma unroll
            for (int r = 0; r < 4; ++r) {
                long m = bm + wr * 128 + i * 16 + quad * 4 + r;
                long n = bn + wc * 64 + j * 16 + l15;
                C[m * kS + n] = acc[i][j][r];
            }
}

// mix = attn @ ctx per batch (plain bf16): K' = S, single segment
__global__ __launch_bounds__(512, 2) void k_gemm_mix(const u16* __restrict__ attnb,
                                                     const u16* __restrict__ ctxT,
                                                     u16* __restrict__ Mixb) {
    const int l = blockIdx.x;
    const int xcd = l & 7, slot = l >> 3;
    const int z = xcd + ((slot >> 4) << 3);
    const int inner = slot & 15;
    const long bn = (long)(inner & 3) * 256;   // H tiles (4)
    const long bm = (long)(inner >> 2) * 256;  // T tiles (4)
    const u16* Ab = attnb + (long)z * kT * kS + bm * kS;
    const u16* Bb = ctxT + (long)z * kH * kS + bn * kS;
    f32x4 acc[8][4] = {};
    gemm_core<32, 32>(Ab, Ab, Ab, kS, Bb, Bb, Bb, kS, acc);
    u16* C = Mixb + (long)z * kT * kH;
    const int t = threadIdx.x, lane = t & 63, wave = t >> 6;
    const int wr = wave >> 2, wc = wave & 3, l15 = lane & 15, quad = lane >> 4;
#pragma unroll
    for (int i = 0; i < 8; ++i)
#pragma unroll
        for (int j = 0; j < 4; ++j)
#pragma unroll
            for (int r = 0; r < 4; ++r) {
                long m = bm + wr * 128 + i * 16 + quad * 4 + r;
                long n = bn + wc * 64 + j * 16 + l15;
                C[m * kH + n] = bf16_rne(acc[i][j][r]);
            }
}

// out = tanh([mix|q] @ lw^T + lb): K' = 2H, segs (mix,lw[:, :H]),(q,lw[:, H:])
__global__ __launch_bounds__(512, 2) void k_gemm_out(const u16* __restrict__ mixc,
                                                     const u16* __restrict__ qc,
                                                     const u16* __restrict__ lwb,
                                                     const float* __restrict__ bias,
                                                     float* __restrict__ Out) {
    const long bm = (long)blockIdx.y * 256, bn = (long)blockIdx.x * 256;
    f32x4 acc[8][4] = {};
    gemm_core<32, 16>(mixc + bm * kH, qc + bm * kH, qc + bm * kH, kH,
                      lwb + bn * 2 * kH, lwb + bn * 2 * kH + kH, lwb + bn * 2 * kH + kH,
                      2 * kH, acc);
    const int t = threadIdx.x, lane = t & 63, wave = t >> 6;
    const int wr = wave >> 2, wc = wave & 3, l15 = lane & 15, quad = lane >> 4;
#pragma unroll
    for (int j = 0; j < 4; ++j) {
        long n = bn + wc * 64 + j * 16 + l15;
        float bj = bias[n];
#pragma unroll
        for (int i = 0; i < 8; ++i)
#pragma unroll
            for (int r = 0; r < 4; ++r) {
                long m = bm + wr * 128 + i * 16 + quad * 4 + r;
                Out[m * kH + n] = tanhf(acc[i][j][r] + bj);
            }
    }
}

// ---------------- prepasses ----------------
__global__ __launch_bounds__(256) void split_f32(const float* __restrict__ src,
                                                 u16* __restrict__ hi, u16* __restrict__ lo,
                                                 long n4) {
    for (long i = (long)blockIdx.x * 256 + threadIdx.x; i < n4; i += (long)gridDim.x * 256) {
        float4 v = ((const float4*)src)[i];
        u16 h0, l0, h1, l1, h2, l2, h3, l3;
        split2(v.x, h0, l0); split2(v.y, h1, l1);
        split2(v.z, h2, l2); split2(v.w, h3, l3);
        ((ushort4*)hi)[i] = make_ushort4(h0, h1, h2, h3);
        ((ushort4*)lo)[i] = make_ushort4(l0, l1, l2, l3);
    }
}

__global__ __launch_bounds__(256) void cvt_f32(const float* __restrict__ src,
                                               u16* __restrict__ dst, long n4) {
    for (long i = (long)blockIdx.x * 256 + threadIdx.x; i < n4; i += (long)gridDim.x * 256) {
        float4 v = ((const float4*)src)[i];
        ((ushort4*)dst)[i] = make_ushort4(bf16_rne(v.x), bf16_rne(v.y),
                                          bf16_rne(v.z), bf16_rne(v.w));
    }
}

__global__ __launch_bounds__(256) void copy16(const uint4* __restrict__ src,
                                              uint4* __restrict__ dst, long n) {
    for (long i = (long)blockIdx.x * 256 + threadIdx.x; i < n; i += (long)gridDim.x * 256)
        dst[i] = src[i];
}

// bf16 [B,S,H] -> [B,H,S]
__global__ __launch_bounds__(256) void transpose_bf16(const u16* __restrict__ in,
                                                      u16* __restrict__ outp) {
    __shared__ u16 tile[64 * 72];
    const int t = threadIdx.x;
    const u16* src = in + (long)blockIdx.z * kS * kH + (long)(blockIdx.y * 64) * kH
                     + blockIdx.x * 64;
#pragma unroll
    for (int it = 0; it < 2; ++it) {
        int idx = it * 256 + t;
        int s = idx >> 3, hc = (idx & 7) << 3;
        uint4 v = *(const uint4*)(src + (long)s * kH + hc);
        const u16* pv = (const u16*)&v;
#pragma unroll
        for (int k = 0; k < 8; ++k) tile[(hc + k) * 72 + s] = pv[k];
    }
    __syncthreads();
    u16* dst = outp + (long)blockIdx.z * kH * kS + (long)(blockIdx.x * 64) * kS
               + blockIdx.y * 64;
#pragma unroll
    for (int it = 0; it < 2; ++it) {
        int idx = it * 256 + t;
        int h = idx >> 3, sc = (idx & 7) << 3;
        *(uint4*)(dst + (long)h * kS + sc) = *(const uint4*)&tile[h * 72 + sc];
    }
}

// ---------------- softmax over S, in place; emits bf16 copy ----------------
__global__ __launch_bounds__(256) void softmax_rows(float* __restrict__ P,
                                                    u16* __restrict__ Pb) {
    __shared__ float red[4];
    float* p = P + (long)blockIdx.x * kS;
    u16* pb = Pb + (long)blockIdx.x * kS;
    const int t = threadIdx.x;

    float4 v0 = ((const float4*)p)[t];
    float4 v1 = ((const float4*)p)[t + 256];

    float m = fmaxf(fmaxf(fmaxf(v0.x, v0.y), fmaxf(v0.z, v0.w)),
                    fmaxf(fmaxf(v1.x, v1.y), fmaxf(v1.z, v1.w)));
#pragma unroll
    for (int o = 32; o > 0; o >>= 1) m = fmaxf(m, __shfl_xor(m, o));
    if ((t & 63) == 0) red[t >> 6] = m;
    __syncthreads();
    m = fmaxf(fmaxf(red[0], red[1]), fmaxf(red[2], red[3]));
    __syncthreads();

    v0.x = expf(v0.x - m); v0.y = expf(v0.y - m);
    v0.z = expf(v0.z - m); v0.w = expf(v0.w - m);
    v1.x = expf(v1.x - m); v1.y = expf(v1.y - m);
    v1.z = expf(v1.z - m); v1.w = expf(v1.w - m);

    float s = v0.x + v0.y + v0.z + v0.w + v1.x + v1.y + v1.z + v1.w;
#pragma unroll
    for (int o = 32; o > 0; o >>= 1) s += __shfl_xor(s, o);
    if ((t & 63) == 0) red[t >> 6] = s;
    __syncthreads();
    s = red[0] + red[1] + red[2] + red[3];

    const float inv = 1.0f / s;
    v0.x *= inv; v0.y *= inv; v0.z *= inv; v0.w *= inv;
    v1.x *= inv; v1.y *= inv; v1.z *= inv; v1.w *= inv;

    ((float4*)p)[t]       = v0;
    ((float4*)p)[t + 256] = v1;
    ((ushort4*)pb)[t]       = make_ushort4(bf16_rne(v0.x), bf16_rne(v0.y),
                                           bf16_rne(v0.z), bf16_rne(v0.w));
    ((ushort4*)pb)[t + 256] = make_ushort4(bf16_rne(v1.x), bf16_rne(v1.y),
                                           bf16_rne(v1.z), bf16_rne(v1.w));
}

// ---------------------------------------------------------------------------
extern "C" void kernel_launch(void* const* d_in, const int* in_sizes, int n_in,
                              void* d_out, int out_size, void* d_ws, size_t ws_size,
                              hipStream_t stream) {
    (void)in_sizes; (void)n_in; (void)out_size; (void)ws_size;

    const float* outp = (const float*)d_in[0];  // [B,T,H]
    const float* ctx  = (const float*)d_in[1];  // [B,S,H]
    const float* aw   = (const float*)d_in[2];  // [H,H]
    const float* lw   = (const float*)d_in[3];  // [H,2H]
    const float* lb   = (const float*)d_in[4];  // [H]

    float* out  = (float*)d_out;
    float* attn = out + NTH;

    u16* ws = (u16*)d_ws;
    u16* ctx_hi = ws;
    u16* ctx_lo = ws + NSH;
    u16* q_hi = (u16*)out;
    u16* q_lo = q_hi + NTH;
    u16* oh  = (u16*)attn;
    u16* ol  = oh + NTH;
    u16* awh = ol + NTH;
    u16* awl = awh + (long)kH * kH;
    u16* ctxT  = ws + NSH;
    u16* attnb = ws;
    u16* mixb  = q_lo;
    u16* q_c   = ws;
    u16* mix_c = ws + NTH;
    u16* lwb   = ws + 2 * NTH;

    split_f32<<<2048, 256, 0, stream>>>(ctx, ctx_hi, ctx_lo, NSH / 4);
    split_f32<<<2048, 256, 0, stream>>>(outp, oh, ol, NTH / 4);
    split_f32<<<1024, 256, 0, stream>>>(aw, awh, awl, (long)kH * kH / 4);

    k_gemm_q<<<dim3(kH / 256, (kB * kT) / 256), 512, 0, stream>>>(oh, ol, awh, awl,
                                                                  q_hi, q_lo);
    k_gemm_logits<<<512, 512, 0, stream>>>(q_hi, q_lo, ctx_hi, ctx_lo, attn);

    transpose_bf16<<<dim3(kH / 64, kS / 64, kB), 256, 0, stream>>>(ctx_hi, ctxT);
    softmax_rows<<<kB * kT, 256, 0, stream>>>(attn, attnb);

    k_gemm_mix<<<256, 512, 0, stream>>>(attnb, ctxT, mixb);

    copy16<<<2048, 256, 0, stream>>>((const uint4*)q_hi, (uint4*)ws, (2 * NTH) / 8);
    cvt_f32<<<2048, 256, 0, stream>>>(lw, lwb, (long)kH * 2 * kH / 4);

    k_gemm_out<<<dim3(kH / 256, (kB * kT) / 256), 512, 0, stream>>>(mix_c, q_c, lwb, lb, out);
}

// Round 5
// 903.695 us; speedup vs baseline: 1.0850x; 1.0237x over previous
//
#include <hip/hip_runtime.h>
#include <math.h>

typedef short bf16x8 __attribute__((ext_vector_type(8)));
typedef float f32x4 __attribute__((ext_vector_type(4)));
typedef float f32x16 __attribute__((ext_vector_type(16)));
typedef unsigned short u16;

#define AS1 __attribute__((address_space(1)))
#define AS3 __attribute__((address_space(3)))

constexpr int kB = 16, kT = 1024, kS = 2048, kH = 1024;
constexpr long NTH = (long)kB * kT * kH;  // 16.8M elems
constexpr long NSH = (long)kB * kS * kH;  // 33.6M elems

// ---------------- bf16 helpers ----------------
__device__ __forceinline__ u16 bf16_rne(float x) {
    unsigned u = __float_as_uint(x);
    u += 0x7FFFu + ((u >> 16) & 1u);
    return (u16)(u >> 16);
}
__device__ __forceinline__ float bf16_f32(u16 h) {
    return __uint_as_float(((unsigned)h) << 16);
}
__device__ __forceinline__ void split2(float x, u16& hi, u16& lo) {
    hi = bf16_rne(x);
    lo = bf16_rne(x - bf16_f32(hi));
}

// =========================================================================
// Core A (round-2 sync structure, measured 217us/41% on logits), now with
// 32x32x16 MFMA: 32 MFMA/tile/wave instead of 64, same LDS traffic.
// LDS tile: row-major [256][64] u16, 128B rows; logical 16B-unit c at row r
// stored at unit (c ^ (r&7)) (both-sides swizzle via inverse-swizzled
// global source + linear global_load_lds dest).
// Fragment (row, kt, hi32): u16 off = row*64 + ((kt*32 + hi32*16) ^ ((row&7)<<4))/2
// C/D layout (HW-verified): col = lane&31, row = (reg&3) + 8*(reg>>2) + 4*(lane>>5).
// =========================================================================
__device__ __forceinline__ void stage_mat(const u16* __restrict__ g, long ld,
                                          u16* lds, int t, int wave) {
#pragma unroll
    for (int c = 0; c < 4; ++c) {
        int u = c * 512 + t;          // 16B unit, 8 per 128B row
        int r = u >> 3, j = u & 7;
        const u16* src = g + (long)r * ld + ((j ^ (r & 7)) << 3);  // inverse swizzle
        u16* dst = lds + c * 4096 + wave * 512;                    // linear dest
        __builtin_amdgcn_global_load_lds((AS1 void*)src, (AS3 void*)dst, 16, 0, 0);
    }
}

// One 256x256 @ K=64 tile: 32x32x16 MFMA, 8 B-frag reads then 2x(8 A-reads + 16 MFMA).
__device__ __forceinline__ void tile_compute(const u16* As, const u16* Bs,
                                             f32x16 acc[4][2], int wr, int wc,
                                             int l31, const int* cbu) {
    bf16x8 b[2][4];
#pragma unroll
    for (int nj = 0; nj < 2; ++nj) {
        const u16* base = Bs + (wc * 64 + nj * 32 + l31) * 64;
#pragma unroll
        for (int kt = 0; kt < 4; ++kt) b[nj][kt] = *(const bf16x8*)(base + cbu[kt]);
    }
#pragma unroll
    for (int mp = 0; mp < 2; ++mp) {
        bf16x8 a[2][4];
#pragma unroll
        for (int m2 = 0; m2 < 2; ++m2) {
            const u16* base = As + (wr * 128 + (mp * 2 + m2) * 32 + l31) * 64;
#pragma unroll
            for (int kt = 0; kt < 4; ++kt) a[m2][kt] = *(const bf16x8*)(base + cbu[kt]);
        }
        __builtin_amdgcn_s_setprio(1);
#pragma unroll
        for (int kt = 0; kt < 4; ++kt)
#pragma unroll
            for (int nj = 0; nj < 2; ++nj)
#pragma unroll
                for (int m2 = 0; m2 < 2; ++m2)
                    acc[mp * 2 + m2][nj] = __builtin_amdgcn_mfma_f32_32x32x16_bf16(
                        a[m2][kt], b[nj][kt], acc[mp * 2 + m2][nj], 0, 0, 0);
        __builtin_amdgcn_s_setprio(0);
    }
}

#define WAIT_VM(N)                                            \
    asm volatile("s_waitcnt vmcnt(" #N ")" ::: "memory");     \
    __builtin_amdgcn_s_barrier();                             \
    __builtin_amdgcn_sched_barrier(0);

#define POST_BARRIER()                                        \
    __builtin_amdgcn_sched_barrier(0);                        \
    __builtin_amdgcn_s_barrier();                             \
    __builtin_amdgcn_sched_barrier(0);

// NT = K'/64 tiles; TPS = tiles per K-segment. Sources pre-offset to (bm,bn).
template <int NT, int TPS>
__device__ __forceinline__ void gemm_core(const u16* a0, const u16* a1, const u16* a2,
                                          long lda,
                                          const u16* b0, const u16* b1, const u16* b2,
                                          long ldb, f32x16 acc[4][2]) {
    __shared__ u16 As[2][256 * 64], Bs[2][256 * 64];
    const int t = threadIdx.x, lane = t & 63, wave = t >> 6;
    const int wr = wave >> 2, wc = wave & 3;
    const int l31 = lane & 31, hi32 = lane >> 5;
    int cbu[4];
#pragma unroll
    for (int kt = 0; kt < 4; ++kt)
        cbu[kt] = ((kt * 32 + hi32 * 16) ^ ((l31 & 7) << 4)) >> 1;  // u16 offset

    auto srcA = [&](int kt) {
        int seg = kt / TPS;
        const u16* p = (seg == 0) ? a0 : (seg == 1 ? a1 : a2);
        return p + (long)(kt % TPS) * 64;
    };
    auto srcB = [&](int kt) {
        int seg = kt / TPS;
        const u16* p = (seg == 0) ? b0 : (seg == 1 ? b1 : b2);
        return p + (long)(kt % TPS) * 64;
    };

    stage_mat(srcA(0), lda, As[0], t, wave);
    stage_mat(srcB(0), ldb, Bs[0], t, wave);
    __builtin_amdgcn_sched_barrier(0);
    stage_mat(srcA(1), lda, As[1], t, wave);
    stage_mat(srcB(1), ldb, Bs[1], t, wave);
    __builtin_amdgcn_sched_barrier(0);

#pragma unroll 1
    for (int it = 0; it < NT / 2 - 1; ++it) {
        int kt = 2 * it;
        WAIT_VM(8)
        tile_compute(As[0], Bs[0], acc, wr, wc, l31, cbu);
        POST_BARRIER()
        stage_mat(srcA(kt + 2), lda, As[0], t, wave);
        stage_mat(srcB(kt + 2), ldb, Bs[0], t, wave);

        WAIT_VM(8)
        tile_compute(As[1], Bs[1], acc, wr, wc, l31, cbu);
        POST_BARRIER()
        stage_mat(srcA(kt + 3), lda, As[1], t, wave);
        stage_mat(srcB(kt + 3), ldb, Bs[1], t, wave);
    }
    WAIT_VM(8)
    tile_compute(As[0], Bs[0], acc, wr, wc, l31, cbu);
    WAIT_VM(0)
    tile_compute(As[1], Bs[1], acc, wr, wc, l31, cbu);
}

// Epilogue index helpers (32x32 C layout): m-local = (r&3)+8*(r>>2)+4*hi32.
#define EPI_LOOP(body)                                                      \
    _Pragma("unroll")                                                       \
    for (int mi = 0; mi < 4; ++mi)                                          \
        _Pragma("unroll")                                                   \
        for (int nj = 0; nj < 2; ++nj)                                      \
            _Pragma("unroll")                                               \
            for (int r = 0; r < 16; ++r) {                                  \
                long m = bm + wr * 128 + mi * 32 + (r & 3) + 8 * (r >> 2) + 4 * hi32; \
                long n = bn + wc * 64 + nj * 32 + l31;                      \
                body                                                        \
            }

// ---------------- GEMM kernels ----------------
// q = output @ attn_w^T in split precision: K' = 3H, segs (oh,awh),(ol,awh),(oh,awl)
__global__ __launch_bounds__(512, 2) void k_gemm_q(const u16* __restrict__ oh,
                                                   const u16* __restrict__ ol,
                                                   const u16* __restrict__ awh,
                                                   const u16* __restrict__ awl,
                                                   u16* __restrict__ Qhi,
                                                   u16* __restrict__ Qlo) {
    const long bm = (long)blockIdx.y * 256, bn = (long)blockIdx.x * 256;
    f32x16 acc[4][2] = {};
    gemm_core<48, 16>(oh + bm * kH, ol + bm * kH, oh + bm * kH, kH,
                      awh + bn * kH, awh + bn * kH, awl + bn * kH, kH, acc);
    const int t = threadIdx.x, lane = t & 63, wave = t >> 6;
    const int wr = wave >> 2, wc = wave & 3, l31 = lane & 31, hi32 = lane >> 5;
    EPI_LOOP({
        float v = acc[mi][nj][r];
        u16 h = bf16_rne(v);
        Qhi[m * kH + n] = h;
        Qlo[m * kH + n] = bf16_rne(v - bf16_f32(h));
    })
}

// logits = q @ ctx^T per batch, split: K' = 3H, segs (qh,ch),(ql,ch),(qh,cl)
// 1D grid 512, XCD-aware decode: each XCD owns 2 whole batches.
__global__ __launch_bounds__(512, 2) void k_gemm_logits(const u16* __restrict__ Qh,
                                                        const u16* __restrict__ Ql,
                                                        const u16* __restrict__ Ch,
                                                        const u16* __restrict__ Cl,
                                                        float* __restrict__ Cout) {
    const int l = blockIdx.x;
    const int xcd = l & 7, slot = l >> 3;
    const int z = xcd + ((slot >> 5) << 3);
    const int inner = slot & 31;
    const long bn = (long)(inner & 7) * 256;   // S tiles (8)
    const long bm = (long)(inner >> 3) * 256;  // T tiles (4)
    const u16* qh = Qh + (long)z * kT * kH + bm * kH;
    const u16* ql = Ql + (long)z * kT * kH + bm * kH;
    const u16* ch = Ch + (long)z * kS * kH + bn * kH;
    const u16* cl = Cl + (long)z * kS * kH + bn * kH;
    f32x16 acc[4][2] = {};
    gemm_core<48, 16>(qh, ql, qh, kH, ch, ch, cl, kH, acc);
    float* C = Cout + (long)z * kT * kS;
    const int t = threadIdx.x, lane = t & 63, wave = t >> 6;
    const int wr = wave >> 2, wc = wave & 3, l31 = lane & 31, hi32 = lane >> 5;
    EPI_LOOP({ C[m * kS + n] = acc[mi][nj][r]; })
}

// mix = attn @ ctx per batch (plain bf16): K' = S, single segment
__global__ __launch_bounds__(512, 2) void k_gemm_mix(const u16* __restrict__ attnb,
                                                     const u16* __restrict__ ctxT,
                                                     u16* __restrict__ Mixb) {
    const int l = blockIdx.x;
    const int xcd = l & 7, slot = l >> 3;
    const int z = xcd + ((slot >> 4) << 3);
    const int inner = slot & 15;
    const long bn = (long)(inner & 3) * 256;   // H tiles (4)
    const long bm = (long)(inner >> 2) * 256;  // T tiles (4)
    const u16* Ab = attnb + (long)z * kT * kS + bm * kS;
    const u16* Bb = ctxT + (long)z * kH * kS + bn * kS;
    f32x16 acc[4][2] = {};
    gemm_core<32, 32>(Ab, Ab, Ab, kS, Bb, Bb, Bb, kS, acc);
    u16* C = Mixb + (long)z * kT * kH;
    const int t = threadIdx.x, lane = t & 63, wave = t >> 6;
    const int wr = wave >> 2, wc = wave & 3, l31 = lane & 31, hi32 = lane >> 5;
    EPI_LOOP({ C[m * kH + n] = bf16_rne(acc[mi][nj][r]); })
}

// out = tanh([mix|q] @ lw^T + lb): K' = 2H, segs (mix,lw[:, :H]),(q,lw[:, H:])
__global__ __launch_bounds__(512, 2) void k_gemm_out(const u16* __restrict__ mixc,
                                                     const u16* __restrict__ qc,
                                                     const u16* __restrict__ lwb,
                                                     const float* __restrict__ bias,
                                                     float* __restrict__ Out) {
    const long bm = (long)blockIdx.y * 256, bn = (long)blockIdx.x * 256;
    f32x16 acc[4][2] = {};
    gemm_core<32, 16>(mixc + bm * kH, qc + bm * kH, qc + bm * kH, kH,
                      lwb + bn * 2 * kH, lwb + bn * 2 * kH + kH, lwb + bn * 2 * kH + kH,
                      2 * kH, acc);
    const int t = threadIdx.x, lane = t & 63, wave = t >> 6;
    const int wr = wave >> 2, wc = wave & 3, l31 = lane & 31, hi32 = lane >> 5;
    EPI_LOOP({ Out[m * kH + n] = tanhf(acc[mi][nj][r] + bias[n]); })
}

// ---------------- prepasses ----------------
__global__ __launch_bounds__(256) void split_f32(const float* __restrict__ src,
                                                 u16* __restrict__ hi, u16* __restrict__ lo,
                                                 long n4) {
    for (long i = (long)blockIdx.x * 256 + threadIdx.x; i < n4; i += (long)gridDim.x * 256) {
        float4 v = ((const float4*)src)[i];
        u16 h0, l0, h1, l1, h2, l2, h3, l3;
        split2(v.x, h0, l0); split2(v.y, h1, l1);
        split2(v.z, h2, l2); split2(v.w, h3, l3);
        ((ushort4*)hi)[i] = make_ushort4(h0, h1, h2, h3);
        ((ushort4*)lo)[i] = make_ushort4(l0, l1, l2, l3);
    }
}

__global__ __launch_bounds__(256) void cvt_f32(const float* __restrict__ src,
                                               u16* __restrict__ dst, long n4) {
    for (long i = (long)blockIdx.x * 256 + threadIdx.x; i < n4; i += (long)gridDim.x * 256) {
        float4 v = ((const float4*)src)[i];
        ((ushort4*)dst)[i] = make_ushort4(bf16_rne(v.x), bf16_rne(v.y),
                                          bf16_rne(v.z), bf16_rne(v.w));
    }
}

__global__ __launch_bounds__(256) void copy16(const uint4* __restrict__ src,
                                              uint4* __restrict__ dst, long n) {
    for (long i = (long)blockIdx.x * 256 + threadIdx.x; i < n; i += (long)gridDim.x * 256)
        dst[i] = src[i];
}

// bf16 [B,S,H] -> [B,H,S]
__global__ __launch_bounds__(256) void transpose_bf16(const u16* __restrict__ in,
                                                      u16* __restrict__ outp) {
    __shared__ u16 tile[64 * 72];
    const int t = threadIdx.x;
    const u16* src = in + (long)blockIdx.z * kS * kH + (long)(blockIdx.y * 64) * kH
                     + blockIdx.x * 64;
#pragma unroll
    for (int it = 0; it < 2; ++it) {
        int idx = it * 256 + t;
        int s = idx >> 3, hc = (idx & 7) << 3;
        uint4 v = *(const uint4*)(src + (long)s * kH + hc);
        const u16* pv = (const u16*)&v;
#pragma unroll
        for (int k = 0; k < 8; ++k) tile[(hc + k) * 72 + s] = pv[k];
    }
    __syncthreads();
    u16* dst = outp + (long)blockIdx.z * kH * kS + (long)(blockIdx.x * 64) * kS
               + blockIdx.y * 64;
#pragma unroll
    for (int it = 0; it < 2; ++it) {
        int idx = it * 256 + t;
        int h = idx >> 3, sc = (idx & 7) << 3;
        *(uint4*)(dst + (long)h * kS + sc) = *(const uint4*)&tile[h * 72 + sc];
    }
}

// ---------------- softmax over S, in place; emits bf16 copy ----------------
__global__ __launch_bounds__(256) void softmax_rows(float* __restrict__ P,
                                                    u16* __restrict__ Pb) {
    __shared__ float red[4];
    float* p = P + (long)blockIdx.x * kS;
    u16* pb = Pb + (long)blockIdx.x * kS;
    const int t = threadIdx.x;

    float4 v0 = ((const float4*)p)[t];
    float4 v1 = ((const float4*)p)[t + 256];

    float m = fmaxf(fmaxf(fmaxf(v0.x, v0.y), fmaxf(v0.z, v0.w)),
                    fmaxf(fmaxf(v1.x, v1.y), fmaxf(v1.z, v1.w)));
#pragma unroll
    for (int o = 32; o > 0; o >>= 1) m = fmaxf(m, __shfl_xor(m, o));
    if ((t & 63) == 0) red[t >> 6] = m;
    __syncthreads();
    m = fmaxf(fmaxf(red[0], red[1]), fmaxf(red[2], red[3]));
    __syncthreads();

    v0.x = expf(v0.x - m); v0.y = expf(v0.y - m);
    v0.z = expf(v0.z - m); v0.w = expf(v0.w - m);
    v1.x = expf(v1.x - m); v1.y = expf(v1.y - m);
    v1.z = expf(v1.z - m); v1.w = expf(v1.w - m);

    float s = v0.x + v0.y + v0.z + v0.w + v1.x + v1.y + v1.z + v1.w;
#pragma unroll
    for (int o = 32; o > 0; o >>= 1) s += __shfl_xor(s, o);
    if ((t & 63) == 0) red[t >> 6] = s;
    __syncthreads();
    s = red[0] + red[1] + red[2] + red[3];

    const float inv = 1.0f / s;
    v0.x *= inv; v0.y *= inv; v0.z *= inv; v0.w *= inv;
    v1.x *= inv; v1.y *= inv; v1.z *= inv; v1.w *= inv;

    ((float4*)p)[t]       = v0;
    ((float4*)p)[t + 256] = v1;
    ((ushort4*)pb)[t]       = make_ushort4(bf16_rne(v0.x), bf16_rne(v0.y),
                                           bf16_rne(v0.z), bf16_rne(v0.w));
    ((ushort4*)pb)[t + 256] = make_ushort4(bf16_rne(v1.x), bf16_rne(v1.y),
                                           bf16_rne(v1.z), bf16_rne(v1.w));
}

// ---------------------------------------------------------------------------
extern "C" void kernel_launch(void* const* d_in, const int* in_sizes, int n_in,
                              void* d_out, int out_size, void* d_ws, size_t ws_size,
                              hipStream_t stream) {
    (void)in_sizes; (void)n_in; (void)out_size; (void)ws_size;

    const float* outp = (const float*)d_in[0];  // [B,T,H]
    const float* ctx  = (const float*)d_in[1];  // [B,S,H]
    const float* aw   = (const float*)d_in[2];  // [H,H]
    const float* lw   = (const float*)d_in[3];  // [H,2H]
    const float* lb   = (const float*)d_in[4];  // [H]

    float* out  = (float*)d_out;
    float* attn = out + NTH;

    u16* ws = (u16*)d_ws;
    u16* ctx_hi = ws;
    u16* ctx_lo = ws + NSH;
    u16* q_hi = (u16*)out;
    u16* q_lo = q_hi + NTH;
    u16* oh  = (u16*)attn;
    u16* ol  = oh + NTH;
    u16* awh = ol + NTH;
    u16* awl = awh + (long)kH * kH;
    u16* ctxT  = ws + NSH;
    u16* attnb = ws;
    u16* mixb  = q_lo;
    u16* q_c   = ws;
    u16* mix_c = ws + NTH;
    u16* lwb   = ws + 2 * NTH;

    split_f32<<<2048, 256, 0, stream>>>(ctx, ctx_hi, ctx_lo, NSH / 4);
    split_f32<<<2048, 256, 0, stream>>>(outp, oh, ol, NTH / 4);
    split_f32<<<1024, 256, 0, stream>>>(aw, awh, awl, (long)kH * kH / 4);

    k_gemm_q<<<dim3(kH / 256, (kB * kT) / 256), 512, 0, stream>>>(oh, ol, awh, awl,
                                                                  q_hi, q_lo);
    k_gemm_logits<<<512, 512, 0, stream>>>(q_hi, q_lo, ctx_hi, ctx_lo, attn);

    transpose_bf16<<<dim3(kH / 64, kS / 64, kB), 256, 0, stream>>>(ctx_hi, ctxT);
    softmax_rows<<<kB * kT, 256, 0, stream>>>(attn, attnb);

    k_gemm_mix<<<256, 512, 0, stream>>>(attnb, ctxT, mixb);

    copy16<<<2048, 256, 0, stream>>>((const uint4*)q_hi, (uint4*)ws, (2 * NTH) / 8);
    cvt_f32<<<2048, 256, 0, stream>>>(lw, lwb, (long)kH * 2 * kH / 4);

    k_gemm_out<<<dim3(kH / 256, (kB * kT) / 256), 512, 0, stream>>>(mix_c, q_c, lwb, lb, out);
}